// Round 2
// baseline (10225.368 us; speedup 1.0000x reference)
//
#include <hip/hip_runtime.h>
#include <math.h>

#define D 64

// ============================ CSR build ============================

// histogram: deg[dst[i]]++ (deg pre-zeroed)
__global__ __launch_bounds__(256) void k_hist(const int* __restrict__ dst,
                                              int* __restrict__ deg, int E) {
    for (int i = blockIdx.x * blockDim.x + threadIdx.x; i < E; i += gridDim.x * blockDim.x)
        atomicAdd(&deg[dst[i]], 1);
}

// block-level exclusive scan: each block scans 2048 elements (256 thr x 8),
// writes per-element exclusive prefix to out, block total to bsums (if non-null)
__global__ __launch_bounds__(256) void k_scan_block(const int* __restrict__ in,
                                                    int* __restrict__ out,
                                                    int* __restrict__ bsums, int n) {
    __shared__ int ts[256];
    int t = threadIdx.x;
    int base = blockIdx.x * 2048 + t * 8;
    int v[8];
    int s = 0;
#pragma unroll
    for (int k = 0; k < 8; ++k) {
        int idx = base + k;
        v[k] = idx < n ? in[idx] : 0;
        s += v[k];
    }
    ts[t] = s;
    __syncthreads();
    // Hillis-Steele inclusive scan over 256 thread sums
    for (int off = 1; off < 256; off <<= 1) {
        int x = (t >= off) ? ts[t - off] : 0;
        __syncthreads();
        ts[t] += x;
        __syncthreads();
    }
    int excl = ts[t] - s;
    if (bsums && t == 255) bsums[blockIdx.x] = ts[255];
    int run = excl;
#pragma unroll
    for (int k = 0; k < 8; ++k) {
        int idx = base + k;
        if (idx < n) out[idx] = run;
        run += v[k];
    }
}

// rowptr[i] += bsums_excl[i>>11]; cursor[i] = rowptr[i]; rowptr[n] = E
__global__ __launch_bounds__(256) void k_scan_fixup(int* __restrict__ rowptr,
                                                    const int* __restrict__ bsums_excl,
                                                    int* __restrict__ cursor, int n, int E) {
    int i = blockIdx.x * blockDim.x + threadIdx.x;
    if (i < n) {
        int v = rowptr[i] + bsums_excl[i >> 11];
        rowptr[i] = v;
        cursor[i] = v;
    }
    if (i == 0) rowptr[n] = E;
}

// scatter edges into dst-sorted order
__global__ __launch_bounds__(256) void k_scatter(const int* __restrict__ src,
                                                 const int* __restrict__ dst,
                                                 const float* __restrict__ tm,
                                                 int* __restrict__ cursor,
                                                 int* __restrict__ s_out,
                                                 float* __restrict__ t_out, int E) {
    for (int i = blockIdx.x * blockDim.x + threadIdx.x; i < E; i += gridDim.x * blockDim.x) {
        int d = dst[i];
        int pos = atomicAdd(&cursor[d], 1);
        s_out[pos] = src[i];
        t_out[pos] = tm[i];
    }
}

// ============================ node-feature kernels ============================

// out[i] = src[idx[i]] (row gather, 64 floats/row)
__global__ __launch_bounds__(256) void k_gather_rows(const float* __restrict__ src,
                                                     const int* __restrict__ idx,
                                                     float* __restrict__ out, int n) {
    int i = blockIdx.x * blockDim.x + threadIdx.x;
    if (i >= n * D) return;
    int r = i >> 6, c = i & 63;
    out[i] = src[(size_t)idx[r] * D + c];
}

// out[N,64] = in[N,64] @ W[64,64]; 16 rows/block, 4 rows per wave (batched over shared W read)
__global__ __launch_bounds__(256) void k_transform(const float* __restrict__ in,
                                                   const float* __restrict__ W,
                                                   float* __restrict__ out, int n) {
    __shared__ float Ws[D * D];
    int t = threadIdx.x;
#pragma unroll
    for (int i = 0; i < 16; ++i) Ws[i * 256 + t] = W[i * 256 + t];
    __syncthreads();
    int lane = t & 63, wid = t >> 6;
    int base = blockIdx.x * 16 + wid * 4;
    float iv0 = (base + 0 < n) ? in[(size_t)(base + 0) * D + lane] : 0.f;
    float iv1 = (base + 1 < n) ? in[(size_t)(base + 1) * D + lane] : 0.f;
    float iv2 = (base + 2 < n) ? in[(size_t)(base + 2) * D + lane] : 0.f;
    float iv3 = (base + 3 < n) ? in[(size_t)(base + 3) * D + lane] : 0.f;
    float o0 = 0.f, o1 = 0.f, o2 = 0.f, o3 = 0.f;
#pragma unroll
    for (int d = 0; d < D; ++d) {
        float w = Ws[d * D + lane];
        o0 += __shfl(iv0, d) * w;
        o1 += __shfl(iv1, d) * w;
        o2 += __shfl(iv2, d) * w;
        o3 += __shfl(iv3, d) * w;
    }
    if (base + 0 < n) out[(size_t)(base + 0) * D + lane] = o0;
    if (base + 1 < n) out[(size_t)(base + 1) * D + lane] = o1;
    if (base + 2 < n) out[(size_t)(base + 2) * D + lane] = o2;
    if (base + 3 < n) out[(size_t)(base + 3) * D + lane] = o3;
}

// ============================ fused reduce + update ============================
// Per dst node (one wave, 2 nodes/wave batched in the GEMM):
//   for each in-edge: sv = srcF[src]; p = dot(cos(t*ef+eph)+sv, dv)/8; ex = exp(p)
//                     acc += ex*(sv + cos(t*kf+kph)); den += ex        (in registers)
//   a = acc/den (0 if no edges)
//   h[node] = elu(concat([a, h[node]]) @ W2)   via readlane broadcasts + LDS W2
__global__ __launch_bounds__(512) void k_reduce_update(
    const float* __restrict__ srcF, const float* __restrict__ dstF,
    float* __restrict__ h, const int* __restrict__ rowptr,
    const int* __restrict__ esrc, const float* __restrict__ etime,
    const float* __restrict__ efreq, const float* __restrict__ ephase,
    const float* __restrict__ kfreq, const float* __restrict__ kphase,
    const float* __restrict__ W2, int n) {
    __shared__ float Ws[2 * D * D];  // 32 KB
    int t = threadIdx.x;
#pragma unroll
    for (int i = 0; i < 16; ++i) Ws[i * 512 + t] = W2[i * 512 + t];
    __syncthreads();
    int lane = t & 63, wid = t >> 6;  // 8 waves
    float ef = efreq[lane], eph = ephase[lane];
    float kf = kfreq[lane], kph = kphase[lane];

    float aN[2], hN[2];
    int nodes[2];
#pragma unroll
    for (int rep = 0; rep < 2; ++rep) {
        int node = blockIdx.x * 16 + wid * 2 + rep;
        nodes[rep] = node;
        float a = 0.f, hv = 0.f;
        if (node < n) {
            int beg = rowptr[node], end = rowptr[node + 1];
            float dv = dstF[(size_t)node * D + lane];
            float acc = 0.f, den = 0.f;
            for (int j = beg; j < end; ++j) {
                int s = esrc[j];
                float tt = etime[j];
                float sv = srcF[(size_t)s * D + lane];
                float p = (__cosf(fmaf(tt, ef, eph)) + sv) * dv;
#pragma unroll
                for (int off = 32; off; off >>= 1) p += __shfl_xor(p, off);
                float ex = __expf(p * 0.125f);
                acc += ex * (sv + __cosf(fmaf(tt, kf, kph)));
                den += ex;
            }
            float inv = den > 0.f ? 1.f / den : 0.f;
            a = acc * inv;
            hv = h[(size_t)node * D + lane];
        }
        aN[rep] = a;
        hN[rep] = hv;
    }
    // update GEMM, both nodes share each Ws read
    float o0 = 0.f, o1 = 0.f;
#pragma unroll
    for (int d = 0; d < D; ++d) {
        float w = Ws[d * D + lane];
        o0 += __shfl(aN[0], d) * w;
        o1 += __shfl(aN[1], d) * w;
    }
#pragma unroll
    for (int d = 0; d < D; ++d) {
        float w = Ws[(D + d) * D + lane];
        o0 += __shfl(hN[0], d) * w;
        o1 += __shfl(hN[1], d) * w;
    }
    if (nodes[0] < n) h[(size_t)nodes[0] * D + lane] = o0 > 0.f ? o0 : __expf(o0) - 1.f;
    if (nodes[1] < n) h[(size_t)nodes[1] * D + lane] = o1 > 0.f ? o1 : __expf(o1) - 1.f;
}

// ============================ tail ============================

__global__ __launch_bounds__(256) void k_gather_feat(const float* __restrict__ h,
                                                     const int* __restrict__ idx,
                                                     float* __restrict__ feat, int B,
                                                     int colOff, int FW) {
    int i = blockIdx.x * blockDim.x + threadIdx.x;
    if (i >= B * D) return;
    int b = i >> 6, c = i & 63;
    feat[(size_t)b * FW + colOff + c] = h[(size_t)idx[b] * D + c];
}

__global__ __launch_bounds__(64) void k_final(const float* __restrict__ feat,
                                              const float* __restrict__ uW,
                                              const float* __restrict__ dW,
                                              const float* __restrict__ db,
                                              float* __restrict__ out, int B, int FW) {
    __shared__ float fr[512];
    __shared__ float un[D];
    int b = blockIdx.x;
    int c = threadIdx.x;
    for (int i = c; i < FW; i += 64) fr[i] = feat[(size_t)b * FW + i];
    __syncthreads();
    float acc = 0.f;
    for (int d = 0; d < FW; ++d) acc += fr[d] * uW[d * D + c];
    un[c] = acc;
    __syncthreads();
    if (c < 3) {
        float o = db[c];
#pragma unroll
        for (int d = 0; d < D; ++d) o += un[d] * dW[d * 3 + c];
        out[b * 3 + c] = o > 0.f ? o : 0.f;
    }
}

// ============================ launch ============================

static void build_csr(const int* src, const int* dst, const float* tm, int E, int N,
                      int* rowptr, int* srcs, float* times, int* cursor,
                      int* bsums, int* bsums_excl, hipStream_t stream) {
    hipMemsetAsync(cursor, 0, (size_t)N * sizeof(int), stream);
    k_hist<<<1024, 256, 0, stream>>>(dst, cursor, E);
    int nb = (N + 2047) / 2048;
    k_scan_block<<<nb, 256, 0, stream>>>(cursor, rowptr, bsums, N);
    k_scan_block<<<1, 256, 0, stream>>>(bsums, bsums_excl, nullptr, nb);
    k_scan_fixup<<<(N + 255) / 256, 256, 0, stream>>>(rowptr, bsums_excl, cursor, N, E);
    k_scatter<<<1024, 256, 0, stream>>>(src, dst, tm, cursor, srcs, times, E);
}

extern "C" void kernel_launch(void* const* d_in, const int* in_sizes, int n_in,
                              void* d_out, int out_size, void* d_ws, size_t ws_size,
                              hipStream_t stream) {
    const float* user_emb = (const float*)d_in[0];
    const float* item_emb = (const float*)d_in[1];
    const float* Wu       = (const float*)d_in[2];
    const float* Wi       = (const float*)d_in[3];
    const float* Wuu      = (const float*)d_in[4];
    const float* Wii      = (const float*)d_in[5];
    const float* u_freq   = (const float*)d_in[6];
    const float* u_phase  = (const float*)d_in[7];
    const float* uk_freq  = (const float*)d_in[8];
    const float* uk_phase = (const float*)d_in[9];
    const float* i_freq   = (const float*)d_in[10];
    const float* i_phase  = (const float*)d_in[11];
    const float* ik_freq  = (const float*)d_in[12];
    const float* ik_phase = (const float*)d_in[13];
    const float* unified_W = (const float*)d_in[14];
    const float* dense_W   = (const float*)d_in[15];
    const float* dense_b   = (const float*)d_in[16];
    const float* by_time   = (const float*)d_in[17];
    const float* pby_time  = (const float*)d_in[18];
    const int* user_id   = (const int*)d_in[19];
    const int* item_id   = (const int*)d_in[20];
    const int* by_src    = (const int*)d_in[21];
    const int* by_dst    = (const int*)d_in[22];
    const int* pby_src   = (const int*)d_in[23];
    const int* pby_dst   = (const int*)d_in[24];
    const int* user_index = (const int*)d_in[25];
    const int* last_item_index = (const int*)d_in[26];

    const int NU = in_sizes[19];
    const int NI = in_sizes[20];
    const int E  = in_sizes[21];
    const int B  = in_sizes[25];
    const int L  = in_sizes[2] / (D * D);
    const int FW = (L + 1) * D;

    // ---- workspace layout ----
    char* wp = (char*)d_ws;
    auto alloc_f = [&](size_t n) { float* p = (float*)wp; wp += n * sizeof(float); return p; };
    auto alloc_i = [&](size_t n) { int* p = (int*)wp; wp += n * sizeof(int); return p; };
    float* uh     = alloc_f((size_t)NU * D);
    float* ih     = alloc_f((size_t)NI * D);
    float* user_h = alloc_f((size_t)NU * D);
    float* item_h = alloc_f((size_t)NI * D);
    int*   by_rowptr  = alloc_i(NU + 1);
    int*   by_srcs    = alloc_i(E);
    float* by_times   = alloc_f(E);
    int*   pby_rowptr = alloc_i(NI + 1);
    int*   pby_srcs   = alloc_i(E);
    float* pby_times  = alloc_f(E);
    int*   cursor     = alloc_i(NU > NI ? NU : NI);
    int*   bsums      = alloc_i(256);
    int*   bsums_excl = alloc_i(256);
    float* feat       = alloc_f((size_t)B * FW);

    // initial node features
    k_gather_rows<<<(NU * D + 255) / 256, 256, 0, stream>>>(user_emb, user_id, user_h, NU);
    k_gather_rows<<<(NI * D + 255) / 256, 256, 0, stream>>>(item_emb, item_id, item_h, NI);

    // CSR for both relations (dst-sorted)
    build_csr(by_src, by_dst, by_time, E, NU, by_rowptr, by_srcs, by_times,
              cursor, bsums, bsums_excl, stream);
    build_csr(pby_src, pby_dst, pby_time, E, NI, pby_rowptr, pby_srcs, pby_times,
              cursor, bsums, bsums_excl, stream);

    for (int l = 0; l < L; ++l) {
        k_transform<<<(NU + 15) / 16, 256, 0, stream>>>(user_h, Wu + l * D * D, uh, NU);
        k_transform<<<(NI + 15) / 16, 256, 0, stream>>>(item_h, Wi + l * D * D, ih, NI);
        // 'by': item -> user  (update user_h in place)
        k_reduce_update<<<(NU + 15) / 16, 512, 0, stream>>>(
            ih, uh, user_h, by_rowptr, by_srcs, by_times,
            u_freq + l * D, u_phase + l * D, uk_freq + l * D, uk_phase + l * D,
            Wuu + (size_t)l * 2 * D * D, NU);
        // 'pby': user -> item  (update item_h in place)
        k_reduce_update<<<(NI + 15) / 16, 512, 0, stream>>>(
            uh, ih, item_h, pby_rowptr, pby_srcs, pby_times,
            i_freq + l * D, i_phase + l * D, ik_freq + l * D, ik_phase + l * D,
            Wii + (size_t)l * 2 * D * D, NI);
        k_gather_feat<<<(B * D + 255) / 256, 256, 0, stream>>>(user_h, user_index, feat, B,
                                                               l * D, FW);
    }
    k_gather_feat<<<(B * D + 255) / 256, 256, 0, stream>>>(item_h, last_item_index, feat, B,
                                                           L * D, FW);
    k_final<<<B, 64, 0, stream>>>(feat, unified_W, dense_W, dense_b, (float*)d_out, B, FW);
}

// Round 3
// 2342.346 us; speedup vs baseline: 4.3654x; 4.3654x over previous
//
#include <hip/hip_runtime.h>
#include <math.h>

#define D 64
#define CHUNK 16

__device__ __forceinline__ float bf2f(unsigned short u) {
    union { unsigned int i; float f; } v; v.i = ((unsigned int)u) << 16; return v.f;
}
__device__ __forceinline__ unsigned short f2bf(float f) {
    union { float f; unsigned int i; } v; v.f = f;
    unsigned int r = v.i + 0x7FFFu + ((v.i >> 16) & 1u);
    return (unsigned short)(r >> 16);
}

// ============================ CSR build (dst-sort) ============================

__global__ __launch_bounds__(256) void k_hist(const int* __restrict__ dst,
                                              int* __restrict__ deg, int E) {
    for (int i = blockIdx.x * blockDim.x + threadIdx.x; i < E; i += gridDim.x * blockDim.x)
        atomicAdd(&deg[dst[i]], 1);
}

__global__ __launch_bounds__(256) void k_scan_block(const int* __restrict__ in,
                                                    int* __restrict__ out,
                                                    int* __restrict__ bsums, int n) {
    __shared__ int ts[256];
    int t = threadIdx.x;
    int base = blockIdx.x * 2048 + t * 8;
    int v[8];
    int s = 0;
#pragma unroll
    for (int k = 0; k < 8; ++k) {
        int idx = base + k;
        v[k] = idx < n ? in[idx] : 0;
        s += v[k];
    }
    ts[t] = s;
    __syncthreads();
    for (int off = 1; off < 256; off <<= 1) {
        int x = (t >= off) ? ts[t - off] : 0;
        __syncthreads();
        ts[t] += x;
        __syncthreads();
    }
    int excl = ts[t] - s;
    if (bsums && t == 255) bsums[blockIdx.x] = ts[255];
    int run = excl;
#pragma unroll
    for (int k = 0; k < 8; ++k) {
        int idx = base + k;
        if (idx < n) out[idx] = run;
        run += v[k];
    }
}

__global__ __launch_bounds__(256) void k_scan_fixup(int* __restrict__ rowptr,
                                                    const int* __restrict__ bsums_excl,
                                                    int* __restrict__ cursor, int n, int E) {
    int i = blockIdx.x * blockDim.x + threadIdx.x;
    if (i < n) {
        int v = rowptr[i] + bsums_excl[i >> 11];
        rowptr[i] = v;
        cursor[i] = v;
    }
    if (i == 0) rowptr[n] = E;
}

// scatter edges into dst-sorted order (src, time, dst)
__global__ __launch_bounds__(256) void k_scatter(const int* __restrict__ src,
                                                 const int* __restrict__ dst,
                                                 const float* __restrict__ tm,
                                                 int* __restrict__ cursor,
                                                 int* __restrict__ s_out,
                                                 float* __restrict__ t_out,
                                                 int* __restrict__ d_sorted, int E) {
    for (int i = blockIdx.x * blockDim.x + threadIdx.x; i < E; i += gridDim.x * blockDim.x) {
        int d = dst[i];
        int pos = atomicAdd(&cursor[d], 1);
        s_out[pos] = src[i];
        t_out[pos] = tm[i];
        d_sorted[pos] = d;
    }
}

// ============================ node-feature kernels ============================

__global__ __launch_bounds__(256) void k_gather_rows(const float* __restrict__ src,
                                                     const int* __restrict__ idx,
                                                     float* __restrict__ out, int n) {
    int i = blockIdx.x * blockDim.x + threadIdx.x;
    if (i >= n * D) return;
    int r = i >> 6, c = i & 63;
    out[i] = src[(size_t)idx[r] * D + c];
}

// out[N,64](bf16) = in[N,64](f32) @ W[64,64]; 16 rows/block, 4 rows per wave
__global__ __launch_bounds__(256) void k_transform(const float* __restrict__ in,
                                                   const float* __restrict__ W,
                                                   unsigned short* __restrict__ out, int n) {
    __shared__ float Ws[D * D];
    int t = threadIdx.x;
#pragma unroll
    for (int i = 0; i < 16; ++i) Ws[i * 256 + t] = W[i * 256 + t];
    __syncthreads();
    int lane = t & 63, wid = t >> 6;
    int base = blockIdx.x * 16 + wid * 4;
    float iv0 = (base + 0 < n) ? in[(size_t)(base + 0) * D + lane] : 0.f;
    float iv1 = (base + 1 < n) ? in[(size_t)(base + 1) * D + lane] : 0.f;
    float iv2 = (base + 2 < n) ? in[(size_t)(base + 2) * D + lane] : 0.f;
    float iv3 = (base + 3 < n) ? in[(size_t)(base + 3) * D + lane] : 0.f;
    float o0 = 0.f, o1 = 0.f, o2 = 0.f, o3 = 0.f;
#pragma unroll
    for (int d = 0; d < D; ++d) {
        float w = Ws[d * D + lane];
        o0 += __shfl(iv0, d) * w;
        o1 += __shfl(iv1, d) * w;
        o2 += __shfl(iv2, d) * w;
        o3 += __shfl(iv3, d) * w;
    }
    if (base + 0 < n) out[(size_t)(base + 0) * D + lane] = f2bf(o0);
    if (base + 1 < n) out[(size_t)(base + 1) * D + lane] = f2bf(o1);
    if (base + 2 < n) out[(size_t)(base + 2) * D + lane] = f2bf(o2);
    if (base + 3 < n) out[(size_t)(base + 3) * D + lane] = f2bf(o3);
}

// ============================ edge kernel: dst-sorted, run-accumulated ============================
// One wave per CHUNK contiguous dst-sorted edges. Same-dst runs accumulate in
// registers; one atomic flush per run (avg deg ~10 -> ~6x fewer atomic bytes).
__global__ __launch_bounds__(256) void k_edge_sorted(
    const unsigned short* __restrict__ srcF, const unsigned short* __restrict__ dstF,
    const int* __restrict__ esrc, const int* __restrict__ edst,
    const float* __restrict__ et,
    const float* __restrict__ efreq, const float* __restrict__ ephase,
    const float* __restrict__ kfreq, const float* __restrict__ kphase,
    float* __restrict__ agg, float* __restrict__ denom, int E) {
    int lane = threadIdx.x & 63;
    int wave = (blockIdx.x * blockDim.x + threadIdx.x) >> 6;
    int base = wave * CHUNK;
    if (base >= E) return;
    float ef = efreq[lane], eph = ephase[lane];
    float kf = kfreq[lane], kph = kphase[lane];
    float acc = 0.f, den = 0.f, dv = 0.f;
    int cur = -1;
#pragma unroll 4
    for (int j = 0; j < CHUNK; ++j) {
        int e = base + j;
        if (e >= E) break;
        int s = esrc[e];
        int d = edst[e];
        float tt = et[e];
        if (d != cur) {  // wave-uniform branch
            if (cur >= 0) {
                unsafeAtomicAdd(&agg[(size_t)cur * D + lane], acc);
                if (lane == 0) unsafeAtomicAdd(&denom[cur], den);
            }
            acc = 0.f; den = 0.f; cur = d;
            dv = bf2f(dstF[(size_t)d * D + lane]);
        }
        float sv = bf2f(srcF[(size_t)s * D + lane]);
        float p = (__cosf(fmaf(tt, ef, eph)) + sv) * dv;
#pragma unroll
        for (int off = 32; off; off >>= 1) p += __shfl_xor(p, off);
        float ex = __expf(p * 0.125f);
        acc += ex * (sv + __cosf(fmaf(tt, kf, kph)));
        den += ex;
    }
    if (cur >= 0) {
        unsafeAtomicAdd(&agg[(size_t)cur * D + lane], acc);
        if (lane == 0) unsafeAtomicAdd(&denom[cur], den);
    }
}

// ============================ update: h = elu(concat([agg/denom, h]) @ W2) ============================
__global__ __launch_bounds__(256) void k_update(float* __restrict__ h,
                                                const float* __restrict__ agg,
                                                const float* __restrict__ denom,
                                                const float* __restrict__ W2, int n) {
    __shared__ float Ws[2 * D * D];  // 32 KB
    __shared__ float rows[4][2 * D];
    int t = threadIdx.x;
#pragma unroll
    for (int i = 0; i < 32; ++i) Ws[i * 256 + t] = W2[i * 256 + t];
    int r = blockIdx.x * 4 + (t >> 6);
    int c = t & 63;
    if (r < n) {
        float dn = denom[r];
        float inv = dn > 0.f ? 1.f / dn : 0.f;  // empty segment -> agg row = 0
        rows[t >> 6][c] = agg[(size_t)r * D + c] * inv;
        rows[t >> 6][D + c] = h[(size_t)r * D + c];
    }
    __syncthreads();
    if (r >= n) return;
    const float* rw = rows[t >> 6];
    float acc = 0.f;
#pragma unroll
    for (int d = 0; d < 2 * D; ++d) acc += rw[d] * Ws[d * D + c];
    h[(size_t)r * D + c] = acc > 0.f ? acc : __expf(acc) - 1.f;  // elu
}

// ============================ tail ============================

__global__ __launch_bounds__(256) void k_gather_feat(const float* __restrict__ h,
                                                     const int* __restrict__ idx,
                                                     float* __restrict__ feat, int B,
                                                     int colOff, int FW) {
    int i = blockIdx.x * blockDim.x + threadIdx.x;
    if (i >= B * D) return;
    int b = i >> 6, c = i & 63;
    feat[(size_t)b * FW + colOff + c] = h[(size_t)idx[b] * D + c];
}

__global__ __launch_bounds__(64) void k_final(const float* __restrict__ feat,
                                              const float* __restrict__ uW,
                                              const float* __restrict__ dW,
                                              const float* __restrict__ db,
                                              float* __restrict__ out, int B, int FW) {
    __shared__ float fr[512];
    __shared__ float un[D];
    int b = blockIdx.x;
    int c = threadIdx.x;
    for (int i = c; i < FW; i += 64) fr[i] = feat[(size_t)b * FW + i];
    __syncthreads();
    float acc = 0.f;
    for (int d = 0; d < FW; ++d) acc += fr[d] * uW[d * D + c];
    un[c] = acc;
    __syncthreads();
    if (c < 3) {
        float o = db[c];
#pragma unroll
        for (int d = 0; d < D; ++d) o += un[d] * dW[d * 3 + c];
        out[b * 3 + c] = o > 0.f ? o : 0.f;
    }
}

// ============================ launch ============================

static void build_csr(const int* src, const int* dst, const float* tm, int E, int N,
                      int* rowptr, int* srcs, float* times, int* dsts, int* cursor,
                      int* bsums, int* bsums_excl, hipStream_t stream) {
    hipMemsetAsync(cursor, 0, (size_t)N * sizeof(int), stream);
    k_hist<<<1024, 256, 0, stream>>>(dst, cursor, E);
    int nb = (N + 2047) / 2048;
    k_scan_block<<<nb, 256, 0, stream>>>(cursor, rowptr, bsums, N);
    k_scan_block<<<1, 256, 0, stream>>>(bsums, bsums_excl, nullptr, nb);
    k_scan_fixup<<<(N + 255) / 256, 256, 0, stream>>>(rowptr, bsums_excl, cursor, N, E);
    k_scatter<<<1024, 256, 0, stream>>>(src, dst, tm, cursor, srcs, times, dsts, E);
}

extern "C" void kernel_launch(void* const* d_in, const int* in_sizes, int n_in,
                              void* d_out, int out_size, void* d_ws, size_t ws_size,
                              hipStream_t stream) {
    const float* user_emb = (const float*)d_in[0];
    const float* item_emb = (const float*)d_in[1];
    const float* Wu       = (const float*)d_in[2];
    const float* Wi       = (const float*)d_in[3];
    const float* Wuu      = (const float*)d_in[4];
    const float* Wii      = (const float*)d_in[5];
    const float* u_freq   = (const float*)d_in[6];
    const float* u_phase  = (const float*)d_in[7];
    const float* uk_freq  = (const float*)d_in[8];
    const float* uk_phase = (const float*)d_in[9];
    const float* i_freq   = (const float*)d_in[10];
    const float* i_phase  = (const float*)d_in[11];
    const float* ik_freq  = (const float*)d_in[12];
    const float* ik_phase = (const float*)d_in[13];
    const float* unified_W = (const float*)d_in[14];
    const float* dense_W   = (const float*)d_in[15];
    const float* dense_b   = (const float*)d_in[16];
    const float* by_time   = (const float*)d_in[17];
    const float* pby_time  = (const float*)d_in[18];
    const int* user_id   = (const int*)d_in[19];
    const int* item_id   = (const int*)d_in[20];
    const int* by_src    = (const int*)d_in[21];
    const int* by_dst    = (const int*)d_in[22];
    const int* pby_src   = (const int*)d_in[23];
    const int* pby_dst   = (const int*)d_in[24];
    const int* user_index = (const int*)d_in[25];
    const int* last_item_index = (const int*)d_in[26];

    const int NU = in_sizes[19];
    const int NI = in_sizes[20];
    const int E  = in_sizes[21];
    const int B  = in_sizes[25];
    const int L  = in_sizes[2] / (D * D);
    const int FW = (L + 1) * D;

    // ---- workspace layout; zero-region [agg_u|agg_i|denom_u|denom_i] contiguous first ----
    char* wp = (char*)d_ws;
    auto alloc_f = [&](size_t n) { float* p = (float*)wp; wp += n * sizeof(float); return p; };
    auto alloc_i = [&](size_t n) { int* p = (int*)wp; wp += n * sizeof(int); return p; };
    auto alloc_h = [&](size_t n) { unsigned short* p = (unsigned short*)wp; wp += n * sizeof(unsigned short); return p; };
    float* agg_u   = alloc_f((size_t)NU * D);
    float* agg_i   = alloc_f((size_t)NI * D);
    float* denom_u = alloc_f(NU);
    float* denom_i = alloc_f(NI);
    size_t zero_bytes = (size_t)(wp - (char*)d_ws);
    float* user_h = alloc_f((size_t)NU * D);
    float* item_h = alloc_f((size_t)NI * D);
    unsigned short* uh = alloc_h((size_t)NU * D);
    unsigned short* ih = alloc_h((size_t)NI * D);
    int*   by_rowptr  = alloc_i(NU + 1);
    int*   by_srcs    = alloc_i(E);
    float* by_times   = alloc_f(E);
    int*   by_dsts    = alloc_i(E);
    int*   pby_rowptr = alloc_i(NI + 1);
    int*   pby_srcs   = alloc_i(E);
    float* pby_times  = alloc_f(E);
    int*   pby_dsts   = alloc_i(E);
    int*   cursor     = alloc_i(NU > NI ? NU : NI);
    int*   bsums      = alloc_i(256);
    int*   bsums_excl = alloc_i(256);
    float* feat       = alloc_f((size_t)B * FW);

    // initial node features (f32)
    k_gather_rows<<<(NU * D + 255) / 256, 256, 0, stream>>>(user_emb, user_id, user_h, NU);
    k_gather_rows<<<(NI * D + 255) / 256, 256, 0, stream>>>(item_emb, item_id, item_h, NI);

    // dst-sorted edge lists for both relations
    build_csr(by_src, by_dst, by_time, E, NU, by_rowptr, by_srcs, by_times, by_dsts,
              cursor, bsums, bsums_excl, stream);
    build_csr(pby_src, pby_dst, pby_time, E, NI, pby_rowptr, pby_srcs, pby_times, pby_dsts,
              cursor, bsums, bsums_excl, stream);

    const int eblocks = (E + CHUNK * 4 - 1) / (CHUNK * 4);
    for (int l = 0; l < L; ++l) {
        hipMemsetAsync(d_ws, 0, zero_bytes, stream);
        k_transform<<<(NU + 15) / 16, 256, 0, stream>>>(user_h, Wu + l * D * D, uh, NU);
        k_transform<<<(NI + 15) / 16, 256, 0, stream>>>(item_h, Wi + l * D * D, ih, NI);
        // 'by': item -> user
        k_edge_sorted<<<eblocks, 256, 0, stream>>>(
            ih, uh, by_srcs, by_dsts, by_times,
            u_freq + l * D, u_phase + l * D, uk_freq + l * D, uk_phase + l * D,
            agg_u, denom_u, E);
        // 'pby': user -> item
        k_edge_sorted<<<eblocks, 256, 0, stream>>>(
            uh, ih, pby_srcs, pby_dsts, pby_times,
            i_freq + l * D, i_phase + l * D, ik_freq + l * D, ik_phase + l * D,
            agg_i, denom_i, E);
        k_update<<<(NU + 3) / 4, 256, 0, stream>>>(user_h, agg_u, denom_u,
                                                   Wuu + (size_t)l * 2 * D * D, NU);
        k_update<<<(NI + 3) / 4, 256, 0, stream>>>(item_h, agg_i, denom_i,
                                                   Wii + (size_t)l * 2 * D * D, NI);
        k_gather_feat<<<(B * D + 255) / 256, 256, 0, stream>>>(user_h, user_index, feat, B,
                                                               l * D, FW);
    }
    k_gather_feat<<<(B * D + 255) / 256, 256, 0, stream>>>(item_h, last_item_index, feat, B,
                                                           L * D, FW);
    k_final<<<B, 64, 0, stream>>>(feat, unified_W, dense_W, dense_b, (float*)d_out, B, FW);
}